// Round 7
// baseline (646.825 us; speedup 1.0000x reference)
//
#include <hip/hip_runtime.h>

// CTRNN forward, B=256 T=2048 D=32 H=64. ALL tensors fp32.
// r10 = r9(537us) with one change per kernel:
//  - recur post-mortem r9: issue 280cy/step UNCHANGED vs r8 (pk rewrite was a
//    wash: shuffles became movs); 32 readlanes @4cy = 128cy dominate issue.
//    VGPR_Count=60 can't hold w4(64f)+q(32f)+xp(8f) -> allocator demotes.
//    Fix: readlane block shrunk to 8 cols (fill window only); cols 8..63 via
//    the PROVEN pipelined LDS broadcast path extended 8->14 quads, consumed
//    as pk_fma in ascending-column order (bit-identical accumulation).
//    __launch_bounds__(64,1) frees the register budget.
//  - xproj: LDS-pipe-throughput-bound (2048 rows/CU x 8 bcast b128 x ~12cy
//    ~= 82us floor + staging). LDS deleted: wave-uniform x rows read direct
//    from global (L1-resident), 2-row double-buffered prefetch, 32 waves/CU
//    TLP hides latency. Same per-row math order -> bit-identical.
// absmax must stay 0.0078125 (all FMA chains in identical order).

#define Bb 256
#define Tt 2048
#define Dd 32
#define Hh 64

typedef float v2f __attribute__((ext_vector_type(2)));
typedef float v4f __attribute__((ext_vector_type(4)));

static constexpr float ALPHA = (float)(16.67 / 40.0);
static constexpr float OMA   = 1.0f - ALPHA;

static __device__ inline v2f vfma2(v2f a, v2f b, v2f c) {
#if __has_builtin(__builtin_elementwise_fma)
    return __builtin_elementwise_fma(a, b, c);
#else
    v2f r; r.x = fmaf(a.x, b.x, c.x); r.y = fmaf(a.y, b.y, c.y); return r;
#endif
}

// ---------------- Phase A: xq[b][t][h] = dot(x[b][t][:], W_in[h][:]) -------
// grid 4096 = 256 b x 16 tiles(128 rows), block 256 (4 waves, 32 rows each).
// No LDS: x rows are wave-uniform loads straight from global (L1-served),
// double-buffered one row ahead. Row math identical to all passing kernels:
// a01/a23 pk pairs over 8 float4, final (a01.x+a01.y)+(a23.x+a23.y).
__global__ __launch_bounds__(256) void ctrnn_xproj(
    const float* __restrict__ x,
    const float* __restrict__ W_in,
    float* __restrict__ xq)
{
    const int tid  = threadIdx.x;
    const int lane = tid & 63;
    const int wave = tid >> 6;
    const int b    = blockIdx.x >> 4;
    const int tile = blockIdx.x & 15;
    const int r0   = tile * 128 + wave * 32;   // first row of this wave

    v2f w[16];
    const v2f* wrow = reinterpret_cast<const v2f*>(W_in + lane * Dd);
#pragma unroll
    for (int j = 0; j < 16; ++j) w[j] = wrow[j];

    const float4* base = reinterpret_cast<const float4*>(
        x + (size_t)b * Tt * Dd + (size_t)r0 * Dd);      // 8 float4 per row
    float* ob = xq + (size_t)b * Tt * Hh + (size_t)r0 * Hh;

#define XROW(BUF, RIDX)                                                       \
    {                                                                         \
        v2f a01 = {0.f, 0.f}, a23 = {0.f, 0.f};                               \
        _Pragma("unroll")                                                     \
        for (int j = 0; j < 8; ++j) {                                         \
            const float4 xv = (BUF)[j];                                       \
            const v2f x01 = {xv.x, xv.y};                                     \
            const v2f x23 = {xv.z, xv.w};                                     \
            a01 = vfma2(w[2 * j + 0], x01, a01);                              \
            a23 = vfma2(w[2 * j + 1], x23, a23);                              \
        }                                                                     \
        ob[(size_t)(RIDX) * Hh + lane] = (a01.x + a01.y) + (a23.x + a23.y);   \
    }

    float4 ba[8], bb[8];
#pragma unroll
    for (int j = 0; j < 8; ++j) ba[j] = base[j];        // row 0

    for (int i = 0; i < 32; i += 2) {
        const float4* p1 = base + (size_t)(i + 1) * 8;  // row i+1 (<=31, safe)
#pragma unroll
        for (int j = 0; j < 8; ++j) bb[j] = p1[j];
        XROW(ba, i)
        const int i2 = (i < 30) ? (i + 2) : 31;         // clamp dead prefetch
        const float4* p2 = base + (size_t)i2 * 8;
#pragma unroll
        for (int j = 0; j < 8; ++j) ba[j] = p2[j];
        XROW(bb, i + 1)
    }
#undef XROW
}

// ---------------- Phase B (ws path): no-alias recur ------------------------
// cols 0..7 via readlane+fmac (fill window for the LDS latency); cols 8..63
// via 14x ds_read_b128 broadcast of hs[8..63] pipelined 1 iter ahead,
// consumed as pk_fma in ascending-column order (bit-identical accumulation).
__global__ __launch_bounds__(64, 1) void ctrnn_recur_ws(
    const float* __restrict__ b_in,
    const float* __restrict__ W_hh,
    const float* __restrict__ b_hh,
    const float* __restrict__ xq,
    float* __restrict__ out)
{
    const int b    = blockIdx.x;
    const int lane = threadIdx.x;

    __shared__ alignas(16) float hs[Hh];

    // W_hh row of this lane as v4f: w4[k] = W_hh[lane][4k..4k+3]
    v4f w4[16];
    const v4f* wr = reinterpret_cast<const v4f*>(W_hh + lane * Hh);
#pragma unroll
    for (int j = 0; j < 16; ++j) w4[j] = wr[j];

    const float cb = ALPHA * (b_in[lane] + b_hh[lane]);

    const float* xb = xq + (size_t)b * Tt * Hh + lane;
    float*       op = out + (size_t)b * Tt * Hh + lane;

    float xp[8];
#pragma unroll
    for (int j = 0; j < 8; ++j) xp[j] = xb[(size_t)j * Hh];
    const float* lp = xb + 8 * (size_t)Hh;   // refill ptr (row t+8)

    const v4f* h4 = reinterpret_cast<const v4f*>(hs);

    // prologue: h_0 = 0; q0..q13 hold h[8..63] of the upcoming step
    hs[lane] = 0.0f;   // single wave: in-order LDS pipe orders later reads
    v4f q0  = h4[2],  q1  = h4[3],  q2  = h4[4],  q3  = h4[5];
    v4f q4  = h4[6],  q5  = h4[7],  q6  = h4[8],  q7  = h4[9];
    v4f q8  = h4[10], q9  = h4[11], q10 = h4[12], q11 = h4[13];
    v4f q12 = h4[14], q13 = h4[15];

    float hold = 0.0f;
    float pre  = cb;              // fmaf(OMA, 0, cb) == cb exactly
    for (int t = 0; t < Tt; t += 8) {
#pragma unroll
        for (int j = 0; j < 8; ++j) {
            const int hb = __float_as_int(hold);
            float s0 = 0.f, s1 = 0.f, s2 = 0.f, s3 = 0.f;
            // cols 0..7 via readlane (ascending; fills LDS latency window)
#pragma unroll
            for (int k = 0; k < 2; ++k) {
                const float h0 = __int_as_float(__builtin_amdgcn_readlane(hb, 4 * k + 0));
                const float h1 = __int_as_float(__builtin_amdgcn_readlane(hb, 4 * k + 1));
                const float h2 = __int_as_float(__builtin_amdgcn_readlane(hb, 4 * k + 2));
                const float h3 = __int_as_float(__builtin_amdgcn_readlane(hb, 4 * k + 3));
                s0 = fmaf(w4[k][0], h0, s0);   // col 4k
                s1 = fmaf(w4[k][1], h1, s1);   // col 4k+1
                s2 = fmaf(w4[k][2], h2, s2);   // col 4k+2
                s3 = fmaf(w4[k][3], h3, s3);   // col 4k+3
            }
            // cols 8..63 from q via pk_fma; per-accumulator order identical
            // (s0: 8,12..60 asc; s1: 9..61; s2: 10..62; s3: 11..63)
            v2f acc01 = {s0, s1}, acc23 = {s2, s3};
#define QPK(K, Q)                                                              \
            acc01 = vfma2(__builtin_shufflevector(w4[K], w4[K], 0, 1),         \
                          __builtin_shufflevector((Q), (Q), 0, 1), acc01);     \
            acc23 = vfma2(__builtin_shufflevector(w4[K], w4[K], 2, 3),         \
                          __builtin_shufflevector((Q), (Q), 2, 3), acc23);
            QPK( 2, q0)  QPK( 3, q1)  QPK( 4, q2)  QPK( 5, q3)
            QPK( 6, q4)  QPK( 7, q5)  QPK( 8, q6)  QPK( 9, q7)
            QPK(10, q8)  QPK(11, q9)  QPK(12, q10) QPK(13, q11)
            QPK(14, q12) QPK(15, q13)
#undef QPK
            const v2f tt     = acc01 + acc23;           // {s0+s2, s1+s3}
            const float sum  = (tt.x + tt.y) + xp[j];
            const float hnew = fmaxf(fmaf(ALPHA, sum, pre), 0.0f);

            // publish h_t[8..63] for next iter, then immediately issue the
            // broadcast reads; their latency hides under the next readlane
            // block + step tail. sched_barrier pins the issue point.
            hs[lane] = hnew;
            q0  = h4[2];  q1  = h4[3];  q2  = h4[4];  q3  = h4[5];
            q4  = h4[6];  q5  = h4[7];  q6  = h4[8];  q7  = h4[9];
            q8  = h4[10]; q9  = h4[11]; q10 = h4[12]; q11 = h4[13];
            q12 = h4[14]; q13 = h4[15];
            __builtin_amdgcn_sched_barrier(0);

            *op = hnew;                    // h store (distinct buffer from xq)
            op += Hh;
            hold = hnew;
            pre  = fmaf(OMA, hnew, cb);    // next step's pre, in the shadow

            xp[j] = *lp;                   // refill ring 8 ahead (no alias)
            lp += Hh;
        }
    }
    out[(size_t)Bb * Tt * Hh + (size_t)b * Hh + lane] = hold;
}

// ---------------- Phase B (fallback): proven in-place kernel ---------------
__global__ __launch_bounds__(64) void ctrnn_recur_ip(
    const float* __restrict__ b_in,
    const float* __restrict__ W_hh,
    const float* __restrict__ b_hh,
    float* __restrict__ out)
{
    const int b    = blockIdx.x;
    const int lane = threadIdx.x;

    __shared__ alignas(16) float hs[Hh];

    float4 w4[16];
    const float4* wr = reinterpret_cast<const float4*>(W_hh + lane * Hh);
#pragma unroll
    for (int j = 0; j < 16; ++j) w4[j] = wr[j];

    const float cb = ALPHA * (b_in[lane] + b_hh[lane]);

    float* ob = out + (size_t)b * Tt * Hh + lane;

    float xp[8];
#pragma unroll
    for (int j = 0; j < 8; ++j) xp[j] = ob[(size_t)j * Hh];

    float* op       = ob;
    const float* lp = ob + 8 * (size_t)Hh;

    const float4* h4 = reinterpret_cast<const float4*>(hs);

    hs[lane] = 0.0f;
    float4 q0 = h4[8],  q1 = h4[9],  q2 = h4[10], q3 = h4[11];
    float4 q4 = h4[12], q5 = h4[13], q6 = h4[14], q7 = h4[15];

    float hold = 0.0f;
    for (int t = 0; t < Tt; t += 8) {
#pragma unroll
        for (int j = 0; j < 8; ++j) {
            const int hb = __float_as_int(hold);
            float s0 = 0.f, s1 = 0.f, s2 = 0.f, s3 = 0.f;
#pragma unroll
            for (int k = 0; k < 8; ++k) {
                const float h0 = __int_as_float(__builtin_amdgcn_readlane(hb, 4 * k + 0));
                const float h1 = __int_as_float(__builtin_amdgcn_readlane(hb, 4 * k + 1));
                const float h2 = __int_as_float(__builtin_amdgcn_readlane(hb, 4 * k + 2));
                const float h3 = __int_as_float(__builtin_amdgcn_readlane(hb, 4 * k + 3));
                s0 = fmaf(w4[k].x, h0, s0);
                s1 = fmaf(w4[k].y, h1, s1);
                s2 = fmaf(w4[k].z, h2, s2);
                s3 = fmaf(w4[k].w, h3, s3);
            }
            s0 = fmaf(w4[ 8].x, q0.x, s0); s1 = fmaf(w4[ 8].y, q0.y, s1);
            s2 = fmaf(w4[ 8].z, q0.z, s2); s3 = fmaf(w4[ 8].w, q0.w, s3);
            s0 = fmaf(w4[ 9].x, q1.x, s0); s1 = fmaf(w4[ 9].y, q1.y, s1);
            s2 = fmaf(w4[ 9].z, q1.z, s2); s3 = fmaf(w4[ 9].w, q1.w, s3);
            s0 = fmaf(w4[10].x, q2.x, s0); s1 = fmaf(w4[10].y, q2.y, s1);
            s2 = fmaf(w4[10].z, q2.z, s2); s3 = fmaf(w4[10].w, q2.w, s3);
            s0 = fmaf(w4[11].x, q3.x, s0); s1 = fmaf(w4[11].y, q3.y, s1);
            s2 = fmaf(w4[11].z, q3.z, s2); s3 = fmaf(w4[11].w, q3.w, s3);
            s0 = fmaf(w4[12].x, q4.x, s0); s1 = fmaf(w4[12].y, q4.y, s1);
            s2 = fmaf(w4[12].z, q4.z, s2); s3 = fmaf(w4[12].w, q4.w, s3);
            s0 = fmaf(w4[13].x, q5.x, s0); s1 = fmaf(w4[13].y, q5.y, s1);
            s2 = fmaf(w4[13].z, q5.z, s2); s3 = fmaf(w4[13].w, q5.w, s3);
            s0 = fmaf(w4[14].x, q6.x, s0); s1 = fmaf(w4[14].y, q6.y, s1);
            s2 = fmaf(w4[14].z, q6.z, s2); s3 = fmaf(w4[14].w, q6.w, s3);
            s0 = fmaf(w4[15].x, q7.x, s0); s1 = fmaf(w4[15].y, q7.y, s1);
            s2 = fmaf(w4[15].z, q7.z, s2); s3 = fmaf(w4[15].w, q7.w, s3);

            const float sum  = ((s0 + s2) + (s1 + s3)) + xp[j];
            const float hnew = fmaxf(fmaf(ALPHA, sum, fmaf(OMA, hold, cb)), 0.0f);

            hs[lane] = hnew;
            q0 = h4[8];  q1 = h4[9];  q2 = h4[10]; q3 = h4[11];
            q4 = h4[12]; q5 = h4[13]; q6 = h4[14]; q7 = h4[15];

            *op = hnew;
            op += Hh;
            hold = hnew;

            xp[j] = *lp;
            lp += Hh;
        }
    }
    out[(size_t)Bb * Tt * Hh + (size_t)b * Hh + lane] = hold;
}

extern "C" void kernel_launch(void* const* d_in, const int* in_sizes, int n_in,
                              void* d_out, int out_size, void* d_ws, size_t ws_size,
                              hipStream_t stream) {
    const float* x    = (const float*)d_in[0];
    // d_in[1] = seq_lengths (int32): forward value is mask-independent.
    const float* W_in = (const float*)d_in[2];
    const float* b_in = (const float*)d_in[3];
    const float* W_hh = (const float*)d_in[4];
    const float* b_hh = (const float*)d_in[5];
    float* out = (float*)d_out;

    const size_t need = ((size_t)Bb * Tt + 16) * (size_t)Hh * sizeof(float);
    if (d_ws != nullptr && ws_size >= need) {
        float* xq = (float*)d_ws;
        ctrnn_xproj<<<dim3(Bb * 16), dim3(256), 0, stream>>>(x, W_in, xq);
        ctrnn_recur_ws<<<dim3(Bb), dim3(64), 0, stream>>>(b_in, W_hh, b_hh, xq, out);
    } else {
        ctrnn_xproj<<<dim3(Bb * 16), dim3(256), 0, stream>>>(x, W_in, out);
        ctrnn_recur_ip<<<dim3(Bb), dim3(64), 0, stream>>>(b_in, W_hh, b_hh, out);
    }
}

// Round 8
// 556.928 us; speedup vs baseline: 1.1614x; 1.1614x over previous
//
#include <hip/hip_runtime.h>

// CTRNN forward, B=256 T=2048 D=32 H=64. ALL tensors fp32.
// r11:
//  - xproj: REVERTED to the proven r6 LDS-staged version (175us). The direct
//    global-broadcast variant measured 313us (r7) / 324us (r0) twice — dead end.
//  - recur: R=8/Q=14 -> R=16/Q=12. r7 counters: issue 185cy/step (model-exact),
//    stall 205cy = LDS round-trip(~140) + 14-quad arrival span(~12cy/quad)
//    minus only ~80cy of fill. R=16 widens the readlane fill window by 48cy
//    and cuts the arrival span by 24cy; issue grows by ~45cy. Net ~ -60cy.
//  - Column source swap keeps the per-accumulator FMA order IDENTICAL
//    (s0: 0,4,...,60 ascending etc.) -> bit-identical, absmax 0.0078125.

#define Bb 256
#define Tt 2048
#define Dd 32
#define Hh 64

typedef float v2f __attribute__((ext_vector_type(2)));
typedef float v4f __attribute__((ext_vector_type(4)));

static constexpr float ALPHA = (float)(16.67 / 40.0);
static constexpr float OMA   = 1.0f - ALPHA;

static __device__ inline v2f vfma2(v2f a, v2f b, v2f c) {
#if __has_builtin(__builtin_elementwise_fma)
    return __builtin_elementwise_fma(a, b, c);
#else
    v2f r; r.x = fmaf(a.x, b.x, c.x); r.y = fmaf(a.y, b.y, c.y); return r;
#endif
}

// ---------------- Phase A: xq[b][t][h] = dot(x[b][t][:], W_in[h][:]) -------
// EXACT r6 version (measured ~175us): 16KB tile staged coalesced into LDS,
// per-row b128 broadcasts, coalesced stores. Math identical to all passing
// kernels.
__global__ __launch_bounds__(256) void ctrnn_xproj(
    const float* __restrict__ x,
    const float* __restrict__ W_in,
    float* __restrict__ xq)
{
    __shared__ alignas(16) float xs[128 * Dd];   // 16 KB
    const int tid  = threadIdx.x;
    const int lane = tid & 63;
    const int wave = tid >> 6;
    const int b    = blockIdx.x >> 4;
    const int tile = blockIdx.x & 15;
    const int t0   = tile * 128;

    const float4* xsrc = reinterpret_cast<const float4*>(
        x + (size_t)b * Tt * Dd + (size_t)t0 * Dd);
    float4* xdst = reinterpret_cast<float4*>(xs);
#pragma unroll
    for (int r = 0; r < 4; ++r) xdst[r * 256 + tid] = xsrc[r * 256 + tid];

    v2f w[16];
    const v2f* wrow = reinterpret_cast<const v2f*>(W_in + lane * Dd);
#pragma unroll
    for (int j = 0; j < 16; ++j) w[j] = wrow[j];

    __syncthreads();

    float* ob = xq + (size_t)b * Tt * Hh + (size_t)t0 * Hh;
    const int lt0 = wave * 32;
#pragma unroll 2
    for (int i = 0; i < 32; ++i) {
        const float4* xr = reinterpret_cast<const float4*>(xs + (lt0 + i) * Dd);
        v2f a01 = {0.f, 0.f}, a23 = {0.f, 0.f};
#pragma unroll
        for (int j = 0; j < 8; ++j) {
            const float4 xv = xr[j];
            const v2f x01 = {xv.x, xv.y};
            const v2f x23 = {xv.z, xv.w};
            a01 = vfma2(w[2 * j + 0], x01, a01);
            a23 = vfma2(w[2 * j + 1], x23, a23);
        }
        ob[(size_t)(lt0 + i) * Hh + lane] = (a01.x + a01.y) + (a23.x + a23.y);
    }
}

// ---------------- Phase B (ws path): no-alias recur ------------------------
// cols 0..15 via readlane+fmac (fill window covers the LDS round-trip);
// cols 16..63 via 12x ds_read_b128 broadcast of hs[16..63] pipelined 1 iter
// ahead, consumed as pk_fma in ascending-column order (bit-identical).
__global__ __launch_bounds__(64, 1) void ctrnn_recur_ws(
    const float* __restrict__ b_in,
    const float* __restrict__ W_hh,
    const float* __restrict__ b_hh,
    const float* __restrict__ xq,
    float* __restrict__ out)
{
    const int b    = blockIdx.x;
    const int lane = threadIdx.x;

    __shared__ alignas(16) float hs[Hh];

    // W_hh row of this lane as v4f: w4[k] = W_hh[lane][4k..4k+3]
    v4f w4[16];
    const v4f* wr = reinterpret_cast<const v4f*>(W_hh + lane * Hh);
#pragma unroll
    for (int j = 0; j < 16; ++j) w4[j] = wr[j];

    const float cb = ALPHA * (b_in[lane] + b_hh[lane]);

    const float* xb = xq + (size_t)b * Tt * Hh + lane;
    float*       op = out + (size_t)b * Tt * Hh + lane;

    float xp[8];
#pragma unroll
    for (int j = 0; j < 8; ++j) xp[j] = xb[(size_t)j * Hh];
    const float* lp = xb + 8 * (size_t)Hh;   // refill ptr (row t+8)

    const v4f* h4 = reinterpret_cast<const v4f*>(hs);

    // prologue: h_0 = 0; q0..q11 hold h[16..63] of the upcoming step
    hs[lane] = 0.0f;   // single wave: in-order LDS pipe orders later reads
    v4f q0 = h4[4],  q1 = h4[5],  q2  = h4[6],  q3  = h4[7];
    v4f q4 = h4[8],  q5 = h4[9],  q6  = h4[10], q7  = h4[11];
    v4f q8 = h4[12], q9 = h4[13], q10 = h4[14], q11 = h4[15];

    float hold = 0.0f;
    float pre  = cb;              // fmaf(OMA, 0, cb) == cb exactly
    for (int t = 0; t < Tt; t += 8) {
#pragma unroll
        for (int j = 0; j < 8; ++j) {
            const int hb = __float_as_int(hold);
            float s0 = 0.f, s1 = 0.f, s2 = 0.f, s3 = 0.f;
            // cols 0..15 via readlane (ascending; fills LDS latency window)
#pragma unroll
            for (int k = 0; k < 4; ++k) {
                const float h0 = __int_as_float(__builtin_amdgcn_readlane(hb, 4 * k + 0));
                const float h1 = __int_as_float(__builtin_amdgcn_readlane(hb, 4 * k + 1));
                const float h2 = __int_as_float(__builtin_amdgcn_readlane(hb, 4 * k + 2));
                const float h3 = __int_as_float(__builtin_amdgcn_readlane(hb, 4 * k + 3));
                s0 = fmaf(w4[k][0], h0, s0);   // col 4k
                s1 = fmaf(w4[k][1], h1, s1);   // col 4k+1
                s2 = fmaf(w4[k][2], h2, s2);   // col 4k+2
                s3 = fmaf(w4[k][3], h3, s3);   // col 4k+3
            }
            // cols 16..63 from q via pk_fma; per-accumulator order identical
            // (s0: 16,20..60 asc; s1: 17..61; s2: 18..62; s3: 19..63)
            v2f acc01 = {s0, s1}, acc23 = {s2, s3};
#define QPK(K, Q)                                                              \
            acc01 = vfma2(__builtin_shufflevector(w4[K], w4[K], 0, 1),         \
                          __builtin_shufflevector((Q), (Q), 0, 1), acc01);     \
            acc23 = vfma2(__builtin_shufflevector(w4[K], w4[K], 2, 3),         \
                          __builtin_shufflevector((Q), (Q), 2, 3), acc23);
            QPK( 4, q0)  QPK( 5, q1)  QPK( 6, q2)  QPK( 7, q3)
            QPK( 8, q4)  QPK( 9, q5)  QPK(10, q6)  QPK(11, q7)
            QPK(12, q8)  QPK(13, q9)  QPK(14, q10) QPK(15, q11)
#undef QPK
            const v2f tt     = acc01 + acc23;           // {s0+s2, s1+s3}
            const float sum  = (tt.x + tt.y) + xp[j];
            const float hnew = fmaxf(fmaf(ALPHA, sum, pre), 0.0f);

            // publish h_t[16..63] for next iter, then immediately issue the
            // broadcast reads; their latency hides under the next readlane
            // block + step tail. sched_barrier pins the issue point.
            hs[lane] = hnew;
            q0 = h4[4];  q1 = h4[5];  q2  = h4[6];  q3  = h4[7];
            q4 = h4[8];  q5 = h4[9];  q6  = h4[10]; q7  = h4[11];
            q8 = h4[12]; q9 = h4[13]; q10 = h4[14]; q11 = h4[15];
            __builtin_amdgcn_sched_barrier(0);

            *op = hnew;                    // h store (distinct buffer from xq)
            op += Hh;
            hold = hnew;
            pre  = fmaf(OMA, hnew, cb);    // next step's pre, in the shadow

            xp[j] = *lp;                   // refill ring 8 ahead (no alias)
            lp += Hh;
        }
    }
    out[(size_t)Bb * Tt * Hh + (size_t)b * Hh + lane] = hold;
}

// ---------------- Phase B (fallback): proven in-place kernel ---------------
__global__ __launch_bounds__(64) void ctrnn_recur_ip(
    const float* __restrict__ b_in,
    const float* __restrict__ W_hh,
    const float* __restrict__ b_hh,
    float* __restrict__ out)
{
    const int b    = blockIdx.x;
    const int lane = threadIdx.x;

    __shared__ alignas(16) float hs[Hh];

    float4 w4[16];
    const float4* wr = reinterpret_cast<const float4*>(W_hh + lane * Hh);
#pragma unroll
    for (int j = 0; j < 16; ++j) w4[j] = wr[j];

    const float cb = ALPHA * (b_in[lane] + b_hh[lane]);

    float* ob = out + (size_t)b * Tt * Hh + lane;

    float xp[8];
#pragma unroll
    for (int j = 0; j < 8; ++j) xp[j] = ob[(size_t)j * Hh];

    float* op       = ob;
    const float* lp = ob + 8 * (size_t)Hh;

    const float4* h4 = reinterpret_cast<const float4*>(hs);

    hs[lane] = 0.0f;
    float4 q0 = h4[8],  q1 = h4[9],  q2 = h4[10], q3 = h4[11];
    float4 q4 = h4[12], q5 = h4[13], q6 = h4[14], q7 = h4[15];

    float hold = 0.0f;
    for (int t = 0; t < Tt; t += 8) {
#pragma unroll
        for (int j = 0; j < 8; ++j) {
            const int hb = __float_as_int(hold);
            float s0 = 0.f, s1 = 0.f, s2 = 0.f, s3 = 0.f;
#pragma unroll
            for (int k = 0; k < 8; ++k) {
                const float h0 = __int_as_float(__builtin_amdgcn_readlane(hb, 4 * k + 0));
                const float h1 = __int_as_float(__builtin_amdgcn_readlane(hb, 4 * k + 1));
                const float h2 = __int_as_float(__builtin_amdgcn_readlane(hb, 4 * k + 2));
                const float h3 = __int_as_float(__builtin_amdgcn_readlane(hb, 4 * k + 3));
                s0 = fmaf(w4[k].x, h0, s0);
                s1 = fmaf(w4[k].y, h1, s1);
                s2 = fmaf(w4[k].z, h2, s2);
                s3 = fmaf(w4[k].w, h3, s3);
            }
            s0 = fmaf(w4[ 8].x, q0.x, s0); s1 = fmaf(w4[ 8].y, q0.y, s1);
            s2 = fmaf(w4[ 8].z, q0.z, s2); s3 = fmaf(w4[ 8].w, q0.w, s3);
            s0 = fmaf(w4[ 9].x, q1.x, s0); s1 = fmaf(w4[ 9].y, q1.y, s1);
            s2 = fmaf(w4[ 9].z, q1.z, s2); s3 = fmaf(w4[ 9].w, q1.w, s3);
            s0 = fmaf(w4[10].x, q2.x, s0); s1 = fmaf(w4[10].y, q2.y, s1);
            s2 = fmaf(w4[10].z, q2.z, s2); s3 = fmaf(w4[10].w, q2.w, s3);
            s0 = fmaf(w4[11].x, q3.x, s0); s1 = fmaf(w4[11].y, q3.y, s1);
            s2 = fmaf(w4[11].z, q3.z, s2); s3 = fmaf(w4[11].w, q3.w, s3);
            s0 = fmaf(w4[12].x, q4.x, s0); s1 = fmaf(w4[12].y, q4.y, s1);
            s2 = fmaf(w4[12].z, q4.z, s2); s3 = fmaf(w4[12].w, q4.w, s3);
            s0 = fmaf(w4[13].x, q5.x, s0); s1 = fmaf(w4[13].y, q5.y, s1);
            s2 = fmaf(w4[13].z, q5.z, s2); s3 = fmaf(w4[13].w, q5.w, s3);
            s0 = fmaf(w4[14].x, q6.x, s0); s1 = fmaf(w4[14].y, q6.y, s1);
            s2 = fmaf(w4[14].z, q6.z, s2); s3 = fmaf(w4[14].w, q6.w, s3);
            s0 = fmaf(w4[15].x, q7.x, s0); s1 = fmaf(w4[15].y, q7.y, s1);
            s2 = fmaf(w4[15].z, q7.z, s2); s3 = fmaf(w4[15].w, q7.w, s3);

            const float sum  = ((s0 + s2) + (s1 + s3)) + xp[j];
            const float hnew = fmaxf(fmaf(ALPHA, sum, fmaf(OMA, hold, cb)), 0.0f);

            hs[lane] = hnew;
            q0 = h4[8];  q1 = h4[9];  q2 = h4[10]; q3 = h4[11];
            q4 = h4[12]; q5 = h4[13]; q6 = h4[14]; q7 = h4[15];

            *op = hnew;
            op += Hh;
            hold = hnew;

            xp[j] = *lp;
            lp += Hh;
        }
    }
    out[(size_t)Bb * Tt * Hh + (size_t)b * Hh + lane] = hold;
}

extern "C" void kernel_launch(void* const* d_in, const int* in_sizes, int n_in,
                              void* d_out, int out_size, void* d_ws, size_t ws_size,
                              hipStream_t stream) {
    const float* x    = (const float*)d_in[0];
    // d_in[1] = seq_lengths (int32): forward value is mask-independent.
    const float* W_in = (const float*)d_in[2];
    const float* b_in = (const float*)d_in[3];
    const float* W_hh = (const float*)d_in[4];
    const float* b_hh = (const float*)d_in[5];
    float* out = (float*)d_out;

    const size_t need = ((size_t)Bb * Tt + 16) * (size_t)Hh * sizeof(float);
    if (d_ws != nullptr && ws_size >= need) {
        float* xq = (float*)d_ws;
        ctrnn_xproj<<<dim3(Bb * 16), dim3(256), 0, stream>>>(x, W_in, xq);
        ctrnn_recur_ws<<<dim3(Bb), dim3(64), 0, stream>>>(b_in, W_hh, b_hh, xq, out);
    } else {
        ctrnn_xproj<<<dim3(Bb * 16), dim3(256), 0, stream>>>(x, W_in, out);
        ctrnn_recur_ip<<<dim3(Bb), dim3(64), 0, stream>>>(b_in, W_hh, b_hh, out);
    }
}